// Round 1
// baseline (304.486 us; speedup 1.0000x reference)
//
#include <hip/hip_runtime.h>
#include <math.h>

typedef float f4 __attribute__((ext_vector_type(4)));

#define NCg 128
#define NAg 65
#define KNUM 128
#define PDIM 64
#define EDIM 256
#define NEDGE (NCg*NAg*NAg)      // 540800
#define NROWS (NCg*NAg)          // 8320
#define TLO -8.0f
#define TSPAN 144                // xs domain [-8,136]; clamped outside
#define TPB 8                    // table grid points per block

// ---------------------------------------------------------------------------
// Kernel A: build g_d(xs) table.  g_d(xs) = b2[d] + sum_k' w2[d,k'] *
//   ( gelu_exact(sum_k w1[k',k]*phi(xs-k)) + b1[k'] ).
// TPB=8 grid points per block: each w1/w2 register load feeds 8 accumulators,
// cutting the strided w1/w2 re-read traffic (was 96 KB/point) by 8x.
// ---------------------------------------------------------------------------
__global__ void table_kernel(const float* __restrict__ mean,
                             const float* __restrict__ w1,
                             const float* __restrict__ b1,
                             const float* __restrict__ w2,
                             const float* __restrict__ b2,
                             float* __restrict__ T,
                             float invres, int npt)
{
    __shared__ float gb[TPB][KNUM];
    __shared__ float h[TPB][KNUM];
    const int p0 = blockIdx.x * TPB;
    const int t  = threadIdx.x;          // 128 threads

    const float stdv     = mean[1] - mean[0];
    const float inv_astd = 1.0f / (sqrtf(6.28318f) * stdv);

    #pragma unroll
    for (int pp = 0; pp < TPB; ++pp) {
        float xs = TLO + (float)(p0 + pp) * invres;
        float u  = xs - (float)t;
        gb[pp][t] = expf(-0.5f*u*u) * inv_astd;
    }
    __syncthreads();

    {
        float acc[TPB] = {};
        for (int k = 0; k < KNUM; k += 4) {
            f4 wv = *(const f4*)&w1[t*KNUM + k];
            #pragma unroll
            for (int pp = 0; pp < TPB; ++pp) {
                f4 gv = *(const f4*)&gb[pp][k];
                acc[pp] = fmaf(wv.x, gv.x, fmaf(wv.y, gv.y,
                          fmaf(wv.z, gv.z, fmaf(wv.w, gv.w, acc[pp]))));
            }
        }
        float b1t = b1[t];
        #pragma unroll
        for (int pp = 0; pp < TPB; ++pp) {
            float a = acc[pp];
            h[pp][t] = 0.5f*a*(1.0f + erff(a*0.70710678118654752f)) + b1t;
        }
    }
    __syncthreads();

    if (t < PDIM) {
        float b2t = b2[t];
        float o[TPB];
        #pragma unroll
        for (int pp = 0; pp < TPB; ++pp) o[pp] = b2t;
        for (int k = 0; k < KNUM; k += 4) {
            f4 wv = *(const f4*)&w2[t*KNUM + k];
            #pragma unroll
            for (int pp = 0; pp < TPB; ++pp) {
                f4 hv = *(const f4*)&h[pp][k];
                o[pp] = fmaf(wv.x, hv.x, fmaf(wv.y, hv.y,
                        fmaf(wv.z, hv.z, fmaf(wv.w, hv.w, o[pp]))));
            }
        }
        #pragma unroll
        for (int pp = 0; pp < TPB; ++pp) {
            int p = p0 + pp;
            if (p < npt) T[(size_t)p*PDIM + t] = o[pp];
        }
    }
}

// ---------------------------------------------------------------------------
// Kernel B: atom path.  16 rows/block; meta inline; nt stores.
// ---------------------------------------------------------------------------
__launch_bounds__(256)
__global__ void atom_kernel(const float* __restrict__ coord,
                            const float* __restrict__ atom_feat,
                            const int*   __restrict__ etype,
                            const float* __restrict__ mul_w,
                            const float* __restrict__ bias_w,
                            const float* __restrict__ mean,
                            const float* __restrict__ ep_w,
                            const float* __restrict__ ep_b,
                            float* __restrict__ out_atom)
{
    __shared__ float x_s[16*NAg];
    __shared__ float sum_s[16*KNUM];

    const int t  = threadIdx.x;
    const int r0 = blockIdx.x * 16;

    const float stdv     = mean[1] - mean[0];
    const float inv_std  = 1.0f / stdv;
    const float inv_astd = 1.0f / (sqrtf(6.28318f) * stdv);

    for (int it = 0; it < 5; ++it) {
        int item = t + 256*it;
        if (item < 16*NAg) {
            int rr = item / NAg;
            int j  = item - rr*NAg;
            int r  = r0 + rr;
            int c  = r / NAg;
            int i  = r - c*NAg;
            const float* ci = coord + (c*NAg + i)*3;
            const float* cj = coord + (c*NAg + j)*3;
            float dx = cj[0]-ci[0], dy = cj[1]-ci[1], dz = cj[2]-ci[2];
            float dist = sqrtf(dx*dx + dy*dy + dz*dz);
            int t0 = etype[(r*NAg+j)*2+0], t1 = etype[(r*NAg+j)*2+1];
            float mul  = fabsf(mul_w[t0]) + fabsf(mul_w[t1]);
            float bias = bias_w[t0] + bias_w[t1];
            x_s[item] = (mul*dist + bias) * inv_std;
        }
    }
    __syncthreads();

    for (int it = 0; it < 8; ++it) {
        int item = t + 256*it;              // 16*128 = 2048
        int rr = item >> 7;
        int k  = item & 127;
        float fk = (float)k;
        const float* xr = &x_s[rr*NAg];
        float a0=0.f, a1=0.f, a2=0.f, a3=0.f;
        int j = 0;
        for (; j <= NAg-4; j += 4) {
            float u0 = xr[j+0]-fk, u1 = xr[j+1]-fk, u2 = xr[j+2]-fk, u3 = xr[j+3]-fk;
            a0 += exp2f(u0*u0 * -0.72134752f);
            a1 += exp2f(u1*u1 * -0.72134752f);
            a2 += exp2f(u2*u2 * -0.72134752f);
            a3 += exp2f(u3*u3 * -0.72134752f);
        }
        for (; j < NAg; ++j) {
            float u0 = xr[j]-fk;
            a0 += exp2f(u0*u0 * -0.72134752f);
        }
        sum_s[item] = ((a0+a1)+(a2+a3)) * inv_astd;
    }
    __syncthreads();

    {
        const int d = t;                    // 0..255
        float acc[16] = {};
        for (int kk = 0; kk < 32; ++kk) {
            f4 wv4 = *(const f4*)&ep_w[d*KNUM + 4*kk];
            #pragma unroll
            for (int rr = 0; rr < 16; ++rr) {
                f4 sv = *(const f4*)&sum_s[rr*KNUM + 4*kk];
                acc[rr] = fmaf(sv.x, wv4.x,
                          fmaf(sv.y, wv4.y,
                          fmaf(sv.z, wv4.z,
                          fmaf(sv.w, wv4.w, acc[rr]))));
            }
        }
        float epb = ep_b[d];
        #pragma unroll
        for (int rr = 0; rr < 16; ++rr) {
            int o = (r0 + rr)*EDIM + d;
            float af = __builtin_nontemporal_load(&atom_feat[o]);
            __builtin_nontemporal_store(af + acc[rr] + epb, &out_atom[o]);
        }
    }
}

// ---------------------------------------------------------------------------
// Kernel C: attn stream + delta.  Block = 64 edges (1024 f4 units).
// Phase 0: 64 threads compute per-edge meta ONCE (was 16x redundant),
// broadcast idx/fr via LDS.  edge_feature loads hoisted to kernel top and
// nontemporal (no L2 pollution -> T table stays L2-hot).
// ---------------------------------------------------------------------------
__launch_bounds__(256)
__global__ void attn_kernel(const float* __restrict__ coord,
                            const int*   __restrict__ etype,
                            const float* __restrict__ mul_w,
                            const float* __restrict__ bias_w,
                            const float* __restrict__ mean,
                            const float* __restrict__ edge_feat,
                            const float* __restrict__ T,
                            float fres, int npt,
                            float* __restrict__ out_attn,
                            float* __restrict__ out_delta)
{
    __shared__ __attribute__((aligned(16))) float dl[64*3];
    __shared__ int   idx_s[64];
    __shared__ float fr_s[64];

    const int t  = threadIdx.x;
    const int dq = t & 15;
    const int er = t >> 4;                        // 0..15
    const size_t u0 = (size_t)blockIdx.x * 1024;
    const int e0 = blockIdx.x * 64;

    // ---- prefetch edge_feature (nontemporal; latency hides under phase 0) --
    f4 ef[4];
    #pragma unroll
    for (int p = 0; p < 4; ++p)
        ef[p] = __builtin_nontemporal_load((const f4*)edge_feat + u0 + p*256 + t);

    // ---- phase 0: per-edge meta, computed once by 64 threads ----
    if (t < 64) {
        const float inv_std = 1.0f / (mean[1] - mean[0]);
        int eg  = e0 + t;
        int c   = eg / (NAg*NAg);
        int rem = eg - c*(NAg*NAg);
        int i   = rem / NAg;
        int j   = rem - i*NAg;
        const float* ci = coord + (c*NAg + i)*3;
        const float* cj = coord + (c*NAg + j)*3;
        float dx = cj[0]-ci[0], dy = cj[1]-ci[1], dz = cj[2]-ci[2];
        dl[t*3+0] = dx; dl[t*3+1] = dy; dl[t*3+2] = dz;
        float dist = sqrtf(dx*dx + dy*dy + dz*dz);
        int2 tp = *(const int2*)&etype[(size_t)eg*2];
        float mul  = fabsf(mul_w[tp.x]) + fabsf(mul_w[tp.y]);
        float bias = bias_w[tp.x] + bias_w[tp.y];
        float xs = (mul*dist + bias) * inv_std;
        float ti = (xs - TLO) * fres;
        int   ii = (int)ti;
        ii = ii < 0 ? 0 : (ii > npt-2 ? npt-2 : ii);
        float f = ti - (float)ii;
        fr_s[t]  = f < 0.0f ? 0.0f : (f > 1.0f ? 1.0f : f);
        idx_s[t] = ii;
    }
    __syncthreads();

    // ---- delta_pos: 192 floats = 48 coalesced f4 nt stores ----
    if (t < 48) {
        f4 dv = *(const f4*)&dl[t*4];
        __builtin_nontemporal_store(dv, (f4*)(out_delta) + (size_t)blockIdx.x*48 + t);
    }

    // ---- gathers (16 lanes/edge read one contiguous 256B row) ----
    f4 lo[4], hi[4];
    float fr[4];
    #pragma unroll
    for (int p = 0; p < 4; ++p) {
        int le = p*16 + er;
        int ii = idx_s[le];
        fr[p]  = fr_s[le];
        const float* tr = T + (size_t)ii*PDIM + dq*4;
        lo[p] = *(const f4*)tr;
        hi[p] = *(const f4*)(tr + PDIM);
    }

    // ---- lerp + add + nt store ----
    #pragma unroll
    for (int p = 0; p < 4; ++p) {
        f4 o;
        o.x = fmaf(fr[p], hi[p].x - lo[p].x, lo[p].x) + ef[p].x;
        o.y = fmaf(fr[p], hi[p].y - lo[p].y, lo[p].y) + ef[p].y;
        o.z = fmaf(fr[p], hi[p].z - lo[p].z, lo[p].z) + ef[p].z;
        o.w = fmaf(fr[p], hi[p].w - lo[p].w, lo[p].w) + ef[p].w;
        __builtin_nontemporal_store(o, (f4*)out_attn + u0 + p*256 + t);
    }
}

extern "C" void kernel_launch(void* const* d_in, const int* in_sizes, int n_in,
                              void* d_out, int out_size, void* d_ws, size_t ws_size,
                              hipStream_t stream) {
    const float* coord     = (const float*)d_in[0];
    const float* atom_feat = (const float*)d_in[1];
    const int*   etype     = (const int*)  d_in[2];
    const float* edge_feat = (const float*)d_in[3];
    const float* mul_w     = (const float*)d_in[4];
    const float* bias_w    = (const float*)d_in[5];
    const float* mean      = (const float*)d_in[6];
    const float* w1        = (const float*)d_in[7];
    const float* b1        = (const float*)d_in[8];
    const float* w2        = (const float*)d_in[9];
    const float* b2        = (const float*)d_in[10];
    const float* ep_w      = (const float*)d_in[11];
    const float* ep_b      = (const float*)d_in[12];

    float* out = (float*)d_out;
    float* out_atom  = out;
    float* out_attn  = out + (size_t)NCg*NAg*EDIM;
    float* out_delta = out + (size_t)NCg*NAg*EDIM + (size_t)NEDGE*PDIM;

    auto tblBytes = [](int res){ return (size_t)(TSPAN*res+1)*PDIM*4; };
    int res;
    if      (ws_size >= tblBytes(16)) res = 16;   // 590 KB
    else if (ws_size >= tblBytes(4))  res = 4;
    else                              res = 1;
    int npt = TSPAN*res + 1;
    float* Tbl = (float*)d_ws;

    table_kernel<<<(npt + TPB - 1)/TPB, 128, 0, stream>>>(
        mean, w1, b1, w2, b2, Tbl, 1.0f/(float)res, npt);

    atom_kernel<<<NROWS/16, 256, 0, stream>>>(
        coord, atom_feat, etype, mul_w, bias_w, mean, ep_w, ep_b, out_atom);

    attn_kernel<<<NEDGE/64, 256, 0, stream>>>(
        coord, etype, mul_w, bias_w, mean, edge_feat, Tbl,
        (float)res, npt, out_attn, out_delta);
}

// Round 2
// 207.046 us; speedup vs baseline: 1.4706x; 1.4706x over previous
//
#include <hip/hip_runtime.h>
#include <math.h>

typedef float f4 __attribute__((ext_vector_type(4)));

#define NCg 128
#define NAg 65
#define KNUM 128
#define PDIM 64
#define EDIM 256
#define NEDGE (NCg*NAg*NAg)      // 540800
#define NROWS (NCg*NAg)          // 8320
#define TLO -8.0f
#define TSPAN 144                // xs domain [-8,136]; clamped outside
#define TPB 8                    // table grid points per block

// ---------------------------------------------------------------------------
// Kernel A: build g_d(xs) table.  g_d(xs) = b2[d] + sum_k' w2[d,k'] *
//   ( gelu_exact(sum_k w1[k',k]*phi(xs-k)) + b1[k'] ).
// TPB=8 grid points per block: each w1/w2 register load feeds 8 accumulators.
// __launch_bounds__(128) is REQUIRED: without it hipcc budgets VGPRs for a
// 1024-thread block (64 VGPR cap) and the 8-wide unroll spills ~6KB/thread
// of scratch -> 374 MB of HBM traffic, 224 us (round-1 profile).
// ---------------------------------------------------------------------------
__launch_bounds__(128)
__global__ void table_kernel(const float* __restrict__ mean,
                             const float* __restrict__ w1,
                             const float* __restrict__ b1,
                             const float* __restrict__ w2,
                             const float* __restrict__ b2,
                             float* __restrict__ T,
                             float invres, int npt)
{
    __shared__ float gb[TPB][KNUM];
    __shared__ float h[TPB][KNUM];
    const int p0 = blockIdx.x * TPB;
    const int t  = threadIdx.x;          // 128 threads

    const float stdv     = mean[1] - mean[0];
    const float inv_astd = 1.0f / (sqrtf(6.28318f) * stdv);

    #pragma unroll
    for (int pp = 0; pp < TPB; ++pp) {
        float xs = TLO + (float)(p0 + pp) * invres;
        float u  = xs - (float)t;
        gb[pp][t] = expf(-0.5f*u*u) * inv_astd;
    }
    __syncthreads();

    {
        float acc[TPB] = {};
        for (int k = 0; k < KNUM; k += 4) {
            f4 wv = *(const f4*)&w1[t*KNUM + k];
            #pragma unroll
            for (int pp = 0; pp < TPB; ++pp) {
                f4 gv = *(const f4*)&gb[pp][k];
                acc[pp] = fmaf(wv.x, gv.x, fmaf(wv.y, gv.y,
                          fmaf(wv.z, gv.z, fmaf(wv.w, gv.w, acc[pp]))));
            }
        }
        float b1t = b1[t];
        #pragma unroll
        for (int pp = 0; pp < TPB; ++pp) {
            float a = acc[pp];
            h[pp][t] = 0.5f*a*(1.0f + erff(a*0.70710678118654752f)) + b1t;
        }
    }
    __syncthreads();

    if (t < PDIM) {
        float b2t = b2[t];
        float o[TPB];
        #pragma unroll
        for (int pp = 0; pp < TPB; ++pp) o[pp] = b2t;
        for (int k = 0; k < KNUM; k += 4) {
            f4 wv = *(const f4*)&w2[t*KNUM + k];
            #pragma unroll
            for (int pp = 0; pp < TPB; ++pp) {
                f4 hv = *(const f4*)&h[pp][k];
                o[pp] = fmaf(wv.x, hv.x, fmaf(wv.y, hv.y,
                        fmaf(wv.z, hv.z, fmaf(wv.w, hv.w, o[pp]))));
            }
        }
        #pragma unroll
        for (int pp = 0; pp < TPB; ++pp) {
            int p = p0 + pp;
            if (p < npt) T[(size_t)p*PDIM + t] = o[pp];
        }
    }
}

// ---------------------------------------------------------------------------
// Kernel B: atom path.  16 rows/block; meta inline; nt stores.
// ---------------------------------------------------------------------------
__launch_bounds__(256)
__global__ void atom_kernel(const float* __restrict__ coord,
                            const float* __restrict__ atom_feat,
                            const int*   __restrict__ etype,
                            const float* __restrict__ mul_w,
                            const float* __restrict__ bias_w,
                            const float* __restrict__ mean,
                            const float* __restrict__ ep_w,
                            const float* __restrict__ ep_b,
                            float* __restrict__ out_atom)
{
    __shared__ float x_s[16*NAg];
    __shared__ float sum_s[16*KNUM];

    const int t  = threadIdx.x;
    const int r0 = blockIdx.x * 16;

    const float stdv     = mean[1] - mean[0];
    const float inv_std  = 1.0f / stdv;
    const float inv_astd = 1.0f / (sqrtf(6.28318f) * stdv);

    for (int it = 0; it < 5; ++it) {
        int item = t + 256*it;
        if (item < 16*NAg) {
            int rr = item / NAg;
            int j  = item - rr*NAg;
            int r  = r0 + rr;
            int c  = r / NAg;
            int i  = r - c*NAg;
            const float* ci = coord + (c*NAg + i)*3;
            const float* cj = coord + (c*NAg + j)*3;
            float dx = cj[0]-ci[0], dy = cj[1]-ci[1], dz = cj[2]-ci[2];
            float dist = sqrtf(dx*dx + dy*dy + dz*dz);
            int t0 = etype[(r*NAg+j)*2+0], t1 = etype[(r*NAg+j)*2+1];
            float mul  = fabsf(mul_w[t0]) + fabsf(mul_w[t1]);
            float bias = bias_w[t0] + bias_w[t1];
            x_s[item] = (mul*dist + bias) * inv_std;
        }
    }
    __syncthreads();

    for (int it = 0; it < 8; ++it) {
        int item = t + 256*it;              // 16*128 = 2048
        int rr = item >> 7;
        int k  = item & 127;
        float fk = (float)k;
        const float* xr = &x_s[rr*NAg];
        float a0=0.f, a1=0.f, a2=0.f, a3=0.f;
        int j = 0;
        for (; j <= NAg-4; j += 4) {
            float u0 = xr[j+0]-fk, u1 = xr[j+1]-fk, u2 = xr[j+2]-fk, u3 = xr[j+3]-fk;
            a0 += exp2f(u0*u0 * -0.72134752f);
            a1 += exp2f(u1*u1 * -0.72134752f);
            a2 += exp2f(u2*u2 * -0.72134752f);
            a3 += exp2f(u3*u3 * -0.72134752f);
        }
        for (; j < NAg; ++j) {
            float u0 = xr[j]-fk;
            a0 += exp2f(u0*u0 * -0.72134752f);
        }
        sum_s[item] = ((a0+a1)+(a2+a3)) * inv_astd;
    }
    __syncthreads();

    {
        const int d = t;                    // 0..255
        float acc[16] = {};
        for (int kk = 0; kk < 32; ++kk) {
            f4 wv4 = *(const f4*)&ep_w[d*KNUM + 4*kk];
            #pragma unroll
            for (int rr = 0; rr < 16; ++rr) {
                f4 sv = *(const f4*)&sum_s[rr*KNUM + 4*kk];
                acc[rr] = fmaf(sv.x, wv4.x,
                          fmaf(sv.y, wv4.y,
                          fmaf(sv.z, wv4.z,
                          fmaf(sv.w, wv4.w, acc[rr]))));
            }
        }
        float epb = ep_b[d];
        #pragma unroll
        for (int rr = 0; rr < 16; ++rr) {
            int o = (r0 + rr)*EDIM + d;
            float af = __builtin_nontemporal_load(&atom_feat[o]);
            __builtin_nontemporal_store(af + acc[rr] + epb, &out_atom[o]);
        }
    }
}

// ---------------------------------------------------------------------------
// Kernel C: attn stream + delta.  Block = 64 edges (1024 f4 units).
// Phase 0: 64 threads compute per-edge meta ONCE, broadcast idx/fr via LDS.
// edge_feature loads hoisted to kernel top and nontemporal.
// ---------------------------------------------------------------------------
__launch_bounds__(256)
__global__ void attn_kernel(const float* __restrict__ coord,
                            const int*   __restrict__ etype,
                            const float* __restrict__ mul_w,
                            const float* __restrict__ bias_w,
                            const float* __restrict__ mean,
                            const float* __restrict__ edge_feat,
                            const float* __restrict__ T,
                            float fres, int npt,
                            float* __restrict__ out_attn,
                            float* __restrict__ out_delta)
{
    __shared__ __attribute__((aligned(16))) float dl[64*3];
    __shared__ int   idx_s[64];
    __shared__ float fr_s[64];

    const int t  = threadIdx.x;
    const int dq = t & 15;
    const int er = t >> 4;                        // 0..15
    const size_t u0 = (size_t)blockIdx.x * 1024;
    const int e0 = blockIdx.x * 64;

    // ---- prefetch edge_feature (nontemporal; latency hides under phase 0) --
    f4 ef[4];
    #pragma unroll
    for (int p = 0; p < 4; ++p)
        ef[p] = __builtin_nontemporal_load((const f4*)edge_feat + u0 + p*256 + t);

    // ---- phase 0: per-edge meta, computed once by 64 threads ----
    if (t < 64) {
        const float inv_std = 1.0f / (mean[1] - mean[0]);
        int eg  = e0 + t;
        int c   = eg / (NAg*NAg);
        int rem = eg - c*(NAg*NAg);
        int i   = rem / NAg;
        int j   = rem - i*NAg;
        const float* ci = coord + (c*NAg + i)*3;
        const float* cj = coord + (c*NAg + j)*3;
        float dx = cj[0]-ci[0], dy = cj[1]-ci[1], dz = cj[2]-ci[2];
        dl[t*3+0] = dx; dl[t*3+1] = dy; dl[t*3+2] = dz;
        float dist = sqrtf(dx*dx + dy*dy + dz*dz);
        int2 tp = *(const int2*)&etype[(size_t)eg*2];
        float mul  = fabsf(mul_w[tp.x]) + fabsf(mul_w[tp.y]);
        float bias = bias_w[tp.x] + bias_w[tp.y];
        float xs = (mul*dist + bias) * inv_std;
        float ti = (xs - TLO) * fres;
        int   ii = (int)ti;
        ii = ii < 0 ? 0 : (ii > npt-2 ? npt-2 : ii);
        float f = ti - (float)ii;
        fr_s[t]  = f < 0.0f ? 0.0f : (f > 1.0f ? 1.0f : f);
        idx_s[t] = ii;
    }
    __syncthreads();

    // ---- delta_pos: 192 floats = 48 coalesced f4 nt stores ----
    if (t < 48) {
        f4 dv = *(const f4*)&dl[t*4];
        __builtin_nontemporal_store(dv, (f4*)(out_delta) + (size_t)blockIdx.x*48 + t);
    }

    // ---- gathers (16 lanes/edge read one contiguous 256B row) ----
    f4 lo[4], hi[4];
    float fr[4];
    #pragma unroll
    for (int p = 0; p < 4; ++p) {
        int le = p*16 + er;
        int ii = idx_s[le];
        fr[p]  = fr_s[le];
        const float* tr = T + (size_t)ii*PDIM + dq*4;
        lo[p] = *(const f4*)tr;
        hi[p] = *(const f4*)(tr + PDIM);
    }

    // ---- lerp + add + nt store ----
    #pragma unroll
    for (int p = 0; p < 4; ++p) {
        f4 o;
        o.x = fmaf(fr[p], hi[p].x - lo[p].x, lo[p].x) + ef[p].x;
        o.y = fmaf(fr[p], hi[p].y - lo[p].y, lo[p].y) + ef[p].y;
        o.z = fmaf(fr[p], hi[p].z - lo[p].z, lo[p].z) + ef[p].z;
        o.w = fmaf(fr[p], hi[p].w - lo[p].w, lo[p].w) + ef[p].w;
        __builtin_nontemporal_store(o, (f4*)out_attn + u0 + p*256 + t);
    }
}

extern "C" void kernel_launch(void* const* d_in, const int* in_sizes, int n_in,
                              void* d_out, int out_size, void* d_ws, size_t ws_size,
                              hipStream_t stream) {
    const float* coord     = (const float*)d_in[0];
    const float* atom_feat = (const float*)d_in[1];
    const int*   etype     = (const int*)  d_in[2];
    const float* edge_feat = (const float*)d_in[3];
    const float* mul_w     = (const float*)d_in[4];
    const float* bias_w    = (const float*)d_in[5];
    const float* mean      = (const float*)d_in[6];
    const float* w1        = (const float*)d_in[7];
    const float* b1        = (const float*)d_in[8];
    const float* w2        = (const float*)d_in[9];
    const float* b2        = (const float*)d_in[10];
    const float* ep_w      = (const float*)d_in[11];
    const float* ep_b      = (const float*)d_in[12];

    float* out = (float*)d_out;
    float* out_atom  = out;
    float* out_attn  = out + (size_t)NCg*NAg*EDIM;
    float* out_delta = out + (size_t)NCg*NAg*EDIM + (size_t)NEDGE*PDIM;

    auto tblBytes = [](int res){ return (size_t)(TSPAN*res+1)*PDIM*4; };
    int res;
    if      (ws_size >= tblBytes(16)) res = 16;   // 590 KB
    else if (ws_size >= tblBytes(4))  res = 4;
    else                              res = 1;
    int npt = TSPAN*res + 1;
    float* Tbl = (float*)d_ws;

    table_kernel<<<(npt + TPB - 1)/TPB, 128, 0, stream>>>(
        mean, w1, b1, w2, b2, Tbl, 1.0f/(float)res, npt);

    atom_kernel<<<NROWS/16, 256, 0, stream>>>(
        coord, atom_feat, etype, mul_w, bias_w, mean, ep_w, ep_b, out_atom);

    attn_kernel<<<NEDGE/64, 256, 0, stream>>>(
        coord, etype, mul_w, bias_w, mean, edge_feat, Tbl,
        (float)res, npt, out_attn, out_delta);
}

// Round 3
// 135.544 us; speedup vs baseline: 2.2464x; 1.5275x over previous
//
#include <hip/hip_runtime.h>
#include <math.h>

typedef float f4 __attribute__((ext_vector_type(4)));

#define NCg 128
#define NAg 65
#define KNUM 128
#define PDIM 64
#define EDIM 256
#define NEDGE (NCg*NAg*NAg)      // 540800
#define NROWS (NCg*NAg)          // 8320
#define TLO -8.0f
#define TSPAN 144                // xs domain [-8,136]; clamped outside

// ---------------------------------------------------------------------------
// Kernel A: build g_d(xs) table.  g_d(xs) = b2[d] + sum_k' w2[d,k'] *
//   ( gelu_exact(sum_k w1[k',k]*phi(xs-k)) + b1[k'] ).  One block/grid point.
// NOTE: keep this the simple 1-point/block form.  TPB=8 multi-point variants
// (rounds 1-2) spill catastrophically: the x8 unroll + full k-unroll pushes
// live ranges past 256 VGPR -> 123-235 MB scratch traffic, 104-224 us.
// w1/w2 re-reads are L2-resident (96 KB working set) -> not worth batching.
// ---------------------------------------------------------------------------
__launch_bounds__(128)
__global__ void table_kernel(const float* __restrict__ mean,
                             const float* __restrict__ w1,
                             const float* __restrict__ b1,
                             const float* __restrict__ w2,
                             const float* __restrict__ b2,
                             float* __restrict__ T,
                             float invres)
{
    __shared__ float gb[KNUM];
    __shared__ float h[KNUM];
    const int p = blockIdx.x;
    const int t = threadIdx.x;

    const float stdv     = mean[1] - mean[0];
    const float inv_astd = 1.0f / (sqrtf(6.28318f) * stdv);

    const float xs = TLO + (float)p * invres;
    float u = xs - (float)t;
    gb[t] = expf(-0.5f*u*u) * inv_astd;
    __syncthreads();

    float acc = 0.0f;
    for (int k = 0; k < KNUM; k += 4) {
        f4 wv = *(const f4*)&w1[t*KNUM + k];
        f4 gv = *(const f4*)&gb[k];
        acc = fmaf(wv.x, gv.x, fmaf(wv.y, gv.y, fmaf(wv.z, gv.z, fmaf(wv.w, gv.w, acc))));
    }
    h[t] = 0.5f*acc*(1.0f + erff(acc*0.70710678118654752f)) + b1[t];
    __syncthreads();

    if (t < PDIM) {
        float o = b2[t];
        for (int k = 0; k < KNUM; k += 4) {
            f4 wv = *(const f4*)&w2[t*KNUM + k];
            f4 hv = *(const f4*)&h[k];
            o = fmaf(wv.x, hv.x, fmaf(wv.y, hv.y, fmaf(wv.z, hv.z, fmaf(wv.w, hv.w, o))));
        }
        T[(size_t)p*PDIM + t] = o;
    }
}

// ---------------------------------------------------------------------------
// Kernel B: atom path.  16 rows/block; meta inline; nt stores.
// ---------------------------------------------------------------------------
__launch_bounds__(256)
__global__ void atom_kernel(const float* __restrict__ coord,
                            const float* __restrict__ atom_feat,
                            const int*   __restrict__ etype,
                            const float* __restrict__ mul_w,
                            const float* __restrict__ bias_w,
                            const float* __restrict__ mean,
                            const float* __restrict__ ep_w,
                            const float* __restrict__ ep_b,
                            float* __restrict__ out_atom)
{
    __shared__ float x_s[16*NAg];
    __shared__ float sum_s[16*KNUM];

    const int t  = threadIdx.x;
    const int r0 = blockIdx.x * 16;

    const float stdv     = mean[1] - mean[0];
    const float inv_std  = 1.0f / stdv;
    const float inv_astd = 1.0f / (sqrtf(6.28318f) * stdv);

    for (int it = 0; it < 5; ++it) {
        int item = t + 256*it;
        if (item < 16*NAg) {
            int rr = item / NAg;
            int j  = item - rr*NAg;
            int r  = r0 + rr;
            int c  = r / NAg;
            int i  = r - c*NAg;
            const float* ci = coord + (c*NAg + i)*3;
            const float* cj = coord + (c*NAg + j)*3;
            float dx = cj[0]-ci[0], dy = cj[1]-ci[1], dz = cj[2]-ci[2];
            float dist = sqrtf(dx*dx + dy*dy + dz*dz);
            int t0 = etype[(r*NAg+j)*2+0], t1 = etype[(r*NAg+j)*2+1];
            float mul  = fabsf(mul_w[t0]) + fabsf(mul_w[t1]);
            float bias = bias_w[t0] + bias_w[t1];
            x_s[item] = (mul*dist + bias) * inv_std;
        }
    }
    __syncthreads();

    for (int it = 0; it < 8; ++it) {
        int item = t + 256*it;              // 16*128 = 2048
        int rr = item >> 7;
        int k  = item & 127;
        float fk = (float)k;
        const float* xr = &x_s[rr*NAg];
        float a0=0.f, a1=0.f, a2=0.f, a3=0.f;
        int j = 0;
        for (; j <= NAg-4; j += 4) {
            float u0 = xr[j+0]-fk, u1 = xr[j+1]-fk, u2 = xr[j+2]-fk, u3 = xr[j+3]-fk;
            a0 += exp2f(u0*u0 * -0.72134752f);
            a1 += exp2f(u1*u1 * -0.72134752f);
            a2 += exp2f(u2*u2 * -0.72134752f);
            a3 += exp2f(u3*u3 * -0.72134752f);
        }
        for (; j < NAg; ++j) {
            float u0 = xr[j]-fk;
            a0 += exp2f(u0*u0 * -0.72134752f);
        }
        sum_s[item] = ((a0+a1)+(a2+a3)) * inv_astd;
    }
    __syncthreads();

    {
        const int d = t;                    // 0..255
        float acc[16] = {};
        for (int kk = 0; kk < 32; ++kk) {
            f4 wv4 = *(const f4*)&ep_w[d*KNUM + 4*kk];
            #pragma unroll
            for (int rr = 0; rr < 16; ++rr) {
                f4 sv = *(const f4*)&sum_s[rr*KNUM + 4*kk];
                acc[rr] = fmaf(sv.x, wv4.x,
                          fmaf(sv.y, wv4.y,
                          fmaf(sv.z, wv4.z,
                          fmaf(sv.w, wv4.w, acc[rr]))));
            }
        }
        float epb = ep_b[d];
        #pragma unroll
        for (int rr = 0; rr < 16; ++rr) {
            int o = (r0 + rr)*EDIM + d;
            float af = __builtin_nontemporal_load(&atom_feat[o]);
            __builtin_nontemporal_store(af + acc[rr] + epb, &out_atom[o]);
        }
    }
}

// ---------------------------------------------------------------------------
// Kernel C: attn stream + delta.  Block = 64 edges (1024 f4 units).
// Phase 0: 64 threads compute per-edge meta ONCE, broadcast idx/fr via LDS.
// edge_feature loads hoisted to kernel top and nontemporal.
// ---------------------------------------------------------------------------
__launch_bounds__(256)
__global__ void attn_kernel(const float* __restrict__ coord,
                            const int*   __restrict__ etype,
                            const float* __restrict__ mul_w,
                            const float* __restrict__ bias_w,
                            const float* __restrict__ mean,
                            const float* __restrict__ edge_feat,
                            const float* __restrict__ T,
                            float fres, int npt,
                            float* __restrict__ out_attn,
                            float* __restrict__ out_delta)
{
    __shared__ __attribute__((aligned(16))) float dl[64*3];
    __shared__ int   idx_s[64];
    __shared__ float fr_s[64];

    const int t  = threadIdx.x;
    const int dq = t & 15;
    const int er = t >> 4;                        // 0..15
    const size_t u0 = (size_t)blockIdx.x * 1024;
    const int e0 = blockIdx.x * 64;

    // ---- prefetch edge_feature (nontemporal; latency hides under phase 0) --
    f4 ef[4];
    #pragma unroll
    for (int p = 0; p < 4; ++p)
        ef[p] = __builtin_nontemporal_load((const f4*)edge_feat + u0 + p*256 + t);

    // ---- phase 0: per-edge meta, computed once by 64 threads ----
    if (t < 64) {
        const float inv_std = 1.0f / (mean[1] - mean[0]);
        int eg  = e0 + t;
        int c   = eg / (NAg*NAg);
        int rem = eg - c*(NAg*NAg);
        int i   = rem / NAg;
        int j   = rem - i*NAg;
        const float* ci = coord + (c*NAg + i)*3;
        const float* cj = coord + (c*NAg + j)*3;
        float dx = cj[0]-ci[0], dy = cj[1]-ci[1], dz = cj[2]-ci[2];
        dl[t*3+0] = dx; dl[t*3+1] = dy; dl[t*3+2] = dz;
        float dist = sqrtf(dx*dx + dy*dy + dz*dz);
        int2 tp = *(const int2*)&etype[(size_t)eg*2];
        float mul  = fabsf(mul_w[tp.x]) + fabsf(mul_w[tp.y]);
        float bias = bias_w[tp.x] + bias_w[tp.y];
        float xs = (mul*dist + bias) * inv_std;
        float ti = (xs - TLO) * fres;
        int   ii = (int)ti;
        ii = ii < 0 ? 0 : (ii > npt-2 ? npt-2 : ii);
        float f = ti - (float)ii;
        fr_s[t]  = f < 0.0f ? 0.0f : (f > 1.0f ? 1.0f : f);
        idx_s[t] = ii;
    }
    __syncthreads();

    // ---- delta_pos: 192 floats = 48 coalesced f4 nt stores ----
    if (t < 48) {
        f4 dv = *(const f4*)&dl[t*4];
        __builtin_nontemporal_store(dv, (f4*)(out_delta) + (size_t)blockIdx.x*48 + t);
    }

    // ---- gathers (16 lanes/edge read one contiguous 256B row) ----
    f4 lo[4], hi[4];
    float fr[4];
    #pragma unroll
    for (int p = 0; p < 4; ++p) {
        int le = p*16 + er;
        int ii = idx_s[le];
        fr[p]  = fr_s[le];
        const float* tr = T + (size_t)ii*PDIM + dq*4;
        lo[p] = *(const f4*)tr;
        hi[p] = *(const f4*)(tr + PDIM);
    }

    // ---- lerp + add + nt store ----
    #pragma unroll
    for (int p = 0; p < 4; ++p) {
        f4 o;
        o.x = fmaf(fr[p], hi[p].x - lo[p].x, lo[p].x) + ef[p].x;
        o.y = fmaf(fr[p], hi[p].y - lo[p].y, lo[p].y) + ef[p].y;
        o.z = fmaf(fr[p], hi[p].z - lo[p].z, lo[p].z) + ef[p].z;
        o.w = fmaf(fr[p], hi[p].w - lo[p].w, lo[p].w) + ef[p].w;
        __builtin_nontemporal_store(o, (f4*)out_attn + u0 + p*256 + t);
    }
}

extern "C" void kernel_launch(void* const* d_in, const int* in_sizes, int n_in,
                              void* d_out, int out_size, void* d_ws, size_t ws_size,
                              hipStream_t stream) {
    const float* coord     = (const float*)d_in[0];
    const float* atom_feat = (const float*)d_in[1];
    const int*   etype     = (const int*)  d_in[2];
    const float* edge_feat = (const float*)d_in[3];
    const float* mul_w     = (const float*)d_in[4];
    const float* bias_w    = (const float*)d_in[5];
    const float* mean      = (const float*)d_in[6];
    const float* w1        = (const float*)d_in[7];
    const float* b1        = (const float*)d_in[8];
    const float* w2        = (const float*)d_in[9];
    const float* b2        = (const float*)d_in[10];
    const float* ep_w      = (const float*)d_in[11];
    const float* ep_b      = (const float*)d_in[12];

    float* out = (float*)d_out;
    float* out_atom  = out;
    float* out_attn  = out + (size_t)NCg*NAg*EDIM;
    float* out_delta = out + (size_t)NCg*NAg*EDIM + (size_t)NEDGE*PDIM;

    auto tblBytes = [](int res){ return (size_t)(TSPAN*res+1)*PDIM*4; };
    int res;
    if      (ws_size >= tblBytes(16)) res = 16;   // 590 KB
    else if (ws_size >= tblBytes(4))  res = 4;
    else                              res = 1;
    int npt = TSPAN*res + 1;
    float* Tbl = (float*)d_ws;

    table_kernel<<<npt, 128, 0, stream>>>(mean, w1, b1, w2, b2, Tbl, 1.0f/(float)res);

    atom_kernel<<<NROWS/16, 256, 0, stream>>>(
        coord, atom_feat, etype, mul_w, bias_w, mean, ep_w, ep_b, out_atom);

    attn_kernel<<<NEDGE/64, 256, 0, stream>>>(
        coord, etype, mul_w, bias_w, mean, edge_feat, Tbl,
        (float)res, npt, out_attn, out_delta);
}

// Round 4
// 120.841 us; speedup vs baseline: 2.5197x; 1.1217x over previous
//
#include <hip/hip_runtime.h>
#include <math.h>

typedef float f4 __attribute__((ext_vector_type(4)));

#define NCg 128
#define NAg 65
#define KNUM 128
#define PDIM 64
#define EDIM 256
#define NEDGE (NCg*NAg*NAg)      // 540800
#define NROWS (NCg*NAg)          // 8320
#define TLO -8.0f
#define TSPAN 144                // xs domain [-8,136]; clamped outside
#define TPTS 4                   // table grid points per block

// ---------------------------------------------------------------------------
// Kernel A: build g_d(xs) table.  g_d(xs) = b2[d] + sum_k' w2[d,k'] *
//   ( gelu_exact(sum_k w1[k',k]*phi(xs-k)) + b1[k'] ).
// v3: the old per-thread strided row reads (each wave load instr touched 64
// cache lines of w1/w2) thrashed L1 across 2305 blocks.  Now w1 is staged in
// LDS in two 32KB k-halves (rows padded to 17 f4 -> conflict-free b128 reads:
// 17*t mod 32 is a bijection), 4 points/block amortize the staging.
// Register state is one f4 accumulator -> no spill (rounds 1-2 lesson:
// register-resident w1 batching spills catastrophically; LDS-resident is the
// safe way to batch).
// ---------------------------------------------------------------------------
__launch_bounds__(128)
__global__ void table_kernel(const float* __restrict__ mean,
                             const float* __restrict__ w1,
                             const float* __restrict__ b1,
                             const float* __restrict__ w2,
                             const float* __restrict__ b2,
                             float* __restrict__ T,
                             float invres, int npt)
{
    __shared__ f4 wbuf[128*17];          // 34.8KB; w1 half [128 rows][16+1 f4]
                                         // reused for w2 as [64 rows][32+1 f4]
    __shared__ f4 gb4[KNUM];             // k-major: gb4[k] = phi for 4 points
    __shared__ f4 h4[KNUM];              // k-major: h4[k']  = h   for 4 points

    const int t  = threadIdx.x;          // 128 threads
    const int p0 = blockIdx.x * TPTS;

    const float stdv     = mean[1] - mean[0];
    const float inv_astd = 1.0f / (sqrtf(6.28318f) * stdv);

    // gb for 4 points, k-major interleaved (thread t handles k=t)
    {
        f4 g;
        float u0 = TLO + (float)(p0+0)*invres - (float)t;
        float u1 = TLO + (float)(p0+1)*invres - (float)t;
        float u2 = TLO + (float)(p0+2)*invres - (float)t;
        float u3 = TLO + (float)(p0+3)*invres - (float)t;
        g.x = expf(-0.5f*u0*u0) * inv_astd;
        g.y = expf(-0.5f*u1*u1) * inv_astd;
        g.z = expf(-0.5f*u2*u2) * inv_astd;
        g.w = expf(-0.5f*u3*u3) * inv_astd;
        gb4[t] = g;
    }

    // phase 1: acc[pp] = sum_k w1[t][k] * gb[pp][k], staged in two k-halves
    f4 acc = {0.f, 0.f, 0.f, 0.f};
    for (int H = 0; H < 2; ++H) {
        __syncthreads();                       // protect wbuf reuse
        // stage w1[:, H*64 : H*64+64] : 2048 f4, 16 per thread, coalesced
        for (int it = 0; it < 16; ++it) {
            int u   = t + 128*it;
            int row = u >> 4;                  // 16 f4 per row-half
            int c4  = u & 15;
            wbuf[row*17 + c4] = ((const f4*)w1)[row*32 + H*16 + c4];
        }
        __syncthreads();
        const f4* wr = &wbuf[t*17];
        #pragma unroll
        for (int kq = 0; kq < 16; ++kq) {
            f4 wv = wr[kq];
            int kb = H*64 + kq*4;
            acc = acc + wv.x * gb4[kb+0];
            acc = acc + wv.y * gb4[kb+1];
            acc = acc + wv.z * gb4[kb+2];
            acc = acc + wv.w * gb4[kb+3];
        }
    }
    {   // exact gelu + b1, store h k-major
        float b1t = b1[t];
        f4 hv;
        hv.x = 0.5f*acc.x*(1.0f + erff(acc.x*0.70710678118654752f)) + b1t;
        hv.y = 0.5f*acc.y*(1.0f + erff(acc.y*0.70710678118654752f)) + b1t;
        hv.z = 0.5f*acc.z*(1.0f + erff(acc.z*0.70710678118654752f)) + b1t;
        hv.w = 0.5f*acc.w*(1.0f + erff(acc.w*0.70710678118654752f)) + b1t;
        h4[t] = hv;
    }
    __syncthreads();
    // stage w2 (64 rows x 128 k = 2048 f4) into wbuf as [64][33]
    for (int it = 0; it < 16; ++it) {
        int u   = t + 128*it;
        int row = u >> 5;                      // 32 f4 per row
        int c4  = u & 31;
        wbuf[row*33 + c4] = ((const f4*)w2)[u];
    }
    __syncthreads();

    if (t < PDIM) {
        float b2t = b2[t];
        f4 o = {b2t, b2t, b2t, b2t};
        const f4* wr = &wbuf[t*33];
        #pragma unroll
        for (int kq = 0; kq < 32; ++kq) {
            f4 wv = wr[kq];
            o = o + wv.x * h4[kq*4+0];
            o = o + wv.y * h4[kq*4+1];
            o = o + wv.z * h4[kq*4+2];
            o = o + wv.w * h4[kq*4+3];
        }
        if (p0+0 < npt) T[(size_t)(p0+0)*PDIM + t] = o.x;
        if (p0+1 < npt) T[(size_t)(p0+1)*PDIM + t] = o.y;
        if (p0+2 < npt) T[(size_t)(p0+2)*PDIM + t] = o.z;
        if (p0+3 < npt) T[(size_t)(p0+3)*PDIM + t] = o.w;
    }
}

// ---------------------------------------------------------------------------
// Kernel B: atom path.  16 rows/block; meta inline; nt stores.
// ---------------------------------------------------------------------------
__launch_bounds__(256)
__global__ void atom_kernel(const float* __restrict__ coord,
                            const float* __restrict__ atom_feat,
                            const int*   __restrict__ etype,
                            const float* __restrict__ mul_w,
                            const float* __restrict__ bias_w,
                            const float* __restrict__ mean,
                            const float* __restrict__ ep_w,
                            const float* __restrict__ ep_b,
                            float* __restrict__ out_atom)
{
    __shared__ float x_s[16*NAg];
    __shared__ float sum_s[16*KNUM];

    const int t  = threadIdx.x;
    const int r0 = blockIdx.x * 16;

    const float stdv     = mean[1] - mean[0];
    const float inv_std  = 1.0f / stdv;
    const float inv_astd = 1.0f / (sqrtf(6.28318f) * stdv);

    for (int it = 0; it < 5; ++it) {
        int item = t + 256*it;
        if (item < 16*NAg) {
            int rr = item / NAg;
            int j  = item - rr*NAg;
            int r  = r0 + rr;
            int c  = r / NAg;
            int i  = r - c*NAg;
            const float* ci = coord + (c*NAg + i)*3;
            const float* cj = coord + (c*NAg + j)*3;
            float dx = cj[0]-ci[0], dy = cj[1]-ci[1], dz = cj[2]-ci[2];
            float dist = sqrtf(dx*dx + dy*dy + dz*dz);
            int t0 = etype[(r*NAg+j)*2+0], t1 = etype[(r*NAg+j)*2+1];
            float mul  = fabsf(mul_w[t0]) + fabsf(mul_w[t1]);
            float bias = bias_w[t0] + bias_w[t1];
            x_s[item] = (mul*dist + bias) * inv_std;
        }
    }
    __syncthreads();

    for (int it = 0; it < 8; ++it) {
        int item = t + 256*it;              // 16*128 = 2048
        int rr = item >> 7;
        int k  = item & 127;
        float fk = (float)k;
        const float* xr = &x_s[rr*NAg];
        float a0=0.f, a1=0.f, a2=0.f, a3=0.f;
        int j = 0;
        for (; j <= NAg-4; j += 4) {
            float u0 = xr[j+0]-fk, u1 = xr[j+1]-fk, u2 = xr[j+2]-fk, u3 = xr[j+3]-fk;
            a0 += exp2f(u0*u0 * -0.72134752f);
            a1 += exp2f(u1*u1 * -0.72134752f);
            a2 += exp2f(u2*u2 * -0.72134752f);
            a3 += exp2f(u3*u3 * -0.72134752f);
        }
        for (; j < NAg; ++j) {
            float u0 = xr[j]-fk;
            a0 += exp2f(u0*u0 * -0.72134752f);
        }
        sum_s[item] = ((a0+a1)+(a2+a3)) * inv_astd;
    }
    __syncthreads();

    {
        const int d = t;                    // 0..255
        float acc[16] = {};
        for (int kk = 0; kk < 32; ++kk) {
            f4 wv4 = *(const f4*)&ep_w[d*KNUM + 4*kk];
            #pragma unroll
            for (int rr = 0; rr < 16; ++rr) {
                f4 sv = *(const f4*)&sum_s[rr*KNUM + 4*kk];
                acc[rr] = fmaf(sv.x, wv4.x,
                          fmaf(sv.y, wv4.y,
                          fmaf(sv.z, wv4.z,
                          fmaf(sv.w, wv4.w, acc[rr]))));
            }
        }
        float epb = ep_b[d];
        #pragma unroll
        for (int rr = 0; rr < 16; ++rr) {
            int o = (r0 + rr)*EDIM + d;
            float af = __builtin_nontemporal_load(&atom_feat[o]);
            __builtin_nontemporal_store(af + acc[rr] + epb, &out_atom[o]);
        }
    }
}

// ---------------------------------------------------------------------------
// Kernel C: attn stream + delta.  Block = 128 edges (2048 f4 units).
// BARRIER-FREE main path (round-3 lesson: the phase0/LDS-broadcast variant
// put two barriers on the critical path and regressed +4us; redundant
// per-lane meta is free in a memory-bound kernel).  ef loads issued first
// (longest latency); T gathers per 4-edge group to cap VGPRs; delta repack
// via LDS after all stores.
// ---------------------------------------------------------------------------
__launch_bounds__(256)
__global__ void attn_kernel(const float* __restrict__ coord,
                            const int*   __restrict__ etype,
                            const float* __restrict__ mul_w,
                            const float* __restrict__ bias_w,
                            const float* __restrict__ mean,
                            const float* __restrict__ edge_feat,
                            const float* __restrict__ T,
                            float fres, int npt,
                            float* __restrict__ out_attn,
                            float* __restrict__ out_delta)
{
    __shared__ __attribute__((aligned(16))) float dl[128*3];

    const int t  = threadIdx.x;
    const int dq = t & 15;
    const int er = t >> 4;                        // 0..15
    const size_t u0 = (size_t)blockIdx.x * 2048;  // f4 units
    const int e0 = blockIdx.x * 128;

    const float inv_std = 1.0f / (mean[1] - mean[0]);

    // ---- edge_feature loads first: longest-latency, fully independent ----
    f4 ef[8];
    #pragma unroll
    for (int p = 0; p < 8; ++p)
        ef[p] = ((const f4*)edge_feat)[u0 + p*256 + t];

    // ---- inline meta -> xs (16-lane redundant, no barrier), delta to LDS --
    float xsv[8];
    #pragma unroll
    for (int p = 0; p < 8; ++p) {
        int eg  = e0 + p*16 + er;
        int c   = eg / (NAg*NAg);
        int rem = eg - c*(NAg*NAg);
        int i   = rem / NAg;
        int j   = rem - i*NAg;
        const float* ci = coord + (c*NAg + i)*3;
        const float* cj = coord + (c*NAg + j)*3;
        float dx = cj[0]-ci[0], dy = cj[1]-ci[1], dz = cj[2]-ci[2];
        if (dq < 3) dl[(p*16+er)*3 + dq] = (dq==0) ? dx : ((dq==1) ? dy : dz);
        float dist = sqrtf(dx*dx + dy*dy + dz*dz);
        int2 tp = *(const int2*)&etype[(size_t)eg*2];
        float mul  = fabsf(mul_w[tp.x]) + fabsf(mul_w[tp.y]);
        float bias = bias_w[tp.x] + bias_w[tp.y];
        xsv[p] = (mul*dist + bias) * inv_std;
    }

    int idx[8]; float fr[8];
    #pragma unroll
    for (int p = 0; p < 8; ++p) {
        float ti = (xsv[p] - TLO) * fres;
        int   i  = (int)ti;
        i = i < 0 ? 0 : (i > npt-2 ? npt-2 : i);
        float f = ti - (float)i;
        fr[p]  = f < 0.0f ? 0.0f : (f > 1.0f ? 1.0f : f);
        idx[p] = i;
    }

    // ---- per 4-edge group: gather (16 lanes/edge read contiguous 512B),
    //      lerp + add + nt store.  Grouped to cap live VGPRs. ----
    #pragma unroll
    for (int g = 0; g < 2; ++g) {
        f4 lo[4], hi[4];
        #pragma unroll
        for (int q = 0; q < 4; ++q) {
            int p = g*4 + q;
            const float* tr = T + (size_t)idx[p]*PDIM + dq*4;
            lo[q] = *(const f4*)tr;
            hi[q] = *(const f4*)(tr + PDIM);
        }
        #pragma unroll
        for (int q = 0; q < 4; ++q) {
            int p = g*4 + q;
            f4 o;
            o.x = fmaf(fr[p], hi[q].x - lo[q].x, lo[q].x) + ef[p].x;
            o.y = fmaf(fr[p], hi[q].y - lo[q].y, lo[q].y) + ef[p].y;
            o.z = fmaf(fr[p], hi[q].z - lo[q].z, lo[q].z) + ef[p].z;
            o.w = fmaf(fr[p], hi[q].w - lo[q].w, lo[q].w) + ef[p].w;
            __builtin_nontemporal_store(o, (f4*)out_attn + u0 + p*256 + t);
        }
    }

    // ---- delta_pos: 384 floats = 96 coalesced f4 nt stores ----
    __syncthreads();
    if (t < 96) {
        f4 dv = *(const f4*)&dl[t*4];
        __builtin_nontemporal_store(dv, (f4*)(out_delta) + (size_t)blockIdx.x*96 + t);
    }
}

extern "C" void kernel_launch(void* const* d_in, const int* in_sizes, int n_in,
                              void* d_out, int out_size, void* d_ws, size_t ws_size,
                              hipStream_t stream) {
    const float* coord     = (const float*)d_in[0];
    const float* atom_feat = (const float*)d_in[1];
    const int*   etype     = (const int*)  d_in[2];
    const float* edge_feat = (const float*)d_in[3];
    const float* mul_w     = (const float*)d_in[4];
    const float* bias_w    = (const float*)d_in[5];
    const float* mean      = (const float*)d_in[6];
    const float* w1        = (const float*)d_in[7];
    const float* b1        = (const float*)d_in[8];
    const float* w2        = (const float*)d_in[9];
    const float* b2        = (const float*)d_in[10];
    const float* ep_w      = (const float*)d_in[11];
    const float* ep_b      = (const float*)d_in[12];

    float* out = (float*)d_out;
    float* out_atom  = out;
    float* out_attn  = out + (size_t)NCg*NAg*EDIM;
    float* out_delta = out + (size_t)NCg*NAg*EDIM + (size_t)NEDGE*PDIM;

    auto tblBytes = [](int res){ return (size_t)(TSPAN*res+1)*PDIM*4; };
    int res;
    if      (ws_size >= tblBytes(16)) res = 16;   // 590 KB
    else if (ws_size >= tblBytes(4))  res = 4;
    else                              res = 1;
    int npt = TSPAN*res + 1;
    float* Tbl = (float*)d_ws;

    table_kernel<<<(npt + TPTS - 1)/TPTS, 128, 0, stream>>>(
        mean, w1, b1, w2, b2, Tbl, 1.0f/(float)res, npt);

    atom_kernel<<<NROWS/16, 256, 0, stream>>>(
        coord, atom_feat, etype, mul_w, bias_w, mean, ep_w, ep_b, out_atom);

    attn_kernel<<<NEDGE/128, 256, 0, stream>>>(
        coord, etype, mul_w, bias_w, mean, edge_feat, Tbl,
        (float)res, npt, out_attn, out_delta);
}